// Round 1
// baseline (2366.732 us; speedup 1.0000x reference)
//
#include <hip/hip_runtime.h>

typedef unsigned short u16;
typedef unsigned int   u32;

// ---------- constants ----------
// B=512 N=196 C=384 H=12 D=32 A=49 W=14, 3C=1152
#define SCALE 0.17677669529663687f

__device__ __forceinline__ float bf2f(u16 u) {
  union { u32 i; float f; } c; c.i = ((u32)u) << 16; return c.f;
}
__device__ __forceinline__ u16 f2bf(float f) {
  union { float f; u32 i; } c; c.f = f;
  u32 x = c.i;
  return (u16)((x + 0x7fffu + ((x >> 16) & 1u)) >> 16);
}

// jax.image.resize bilinear 7->14, half-pixel centers, edge-renormalized:
// i even=2j: inputs (j-1, j) w (0.25, 0.75); i odd=2j+1: (j, j+1) w (0.75, 0.25)
// i=0 -> input 0 w 1.0; i=13 -> input 6 w 1.0
__device__ __forceinline__ void lin_w(int i, int& i0, int& i1, float& w0, float& w1) {
  if (i == 0)       { i0 = 0; i1 = 0; w0 = 1.f;  w1 = 0.f;  }
  else if (i == 13) { i0 = 6; i1 = 6; w0 = 1.f;  w1 = 0.f;  }
  else if (i & 1)   { int j = i >> 1; i0 = j;     i1 = j + 1; w0 = 0.75f; w1 = 0.25f; }
  else              { int j = i >> 1; i0 = j - 1; i1 = j;     w0 = 0.25f; w1 = 0.75f; }
}

// bias1[h][a][n] = bilinear(an_bias[h,a])(y,x) + ah[h,a,y] + aw[h,a,x]
__global__ void k_bias1(const float* __restrict__ an, const float* __restrict__ ah,
                        const float* __restrict__ aw, float* __restrict__ out) {
  int idx = blockIdx.x * 256 + threadIdx.x;
  if (idx >= 12 * 49 * 196) return;
  int n = idx % 196; int a = (idx / 196) % 49; int h = idx / (196 * 49);
  int y = n / 14, x = n % 14;
  int y0, y1, x0, x1; float wy0, wy1, wx0, wx1;
  lin_w(y, y0, y1, wy0, wy1); lin_w(x, x0, x1, wx0, wx1);
  const float* p = an + (h * 49 + a) * 49;  // 7x7 grid
  float v = wy0 * (wx0 * p[y0 * 7 + x0] + wx1 * p[y0 * 7 + x1])
          + wy1 * (wx0 * p[y1 * 7 + x0] + wx1 * p[y1 * 7 + x1]);
  v += ah[(h * 49 + a) * 14 + y] + aw[(h * 49 + a) * 14 + x];
  out[idx] = v;
}

// bias2[h][n][a] = bilinear(na_bias[h,a])(y,x) + ha[h,y,a] + wa[h,x,a]
__global__ void k_bias2(const float* __restrict__ na, const float* __restrict__ ha,
                        const float* __restrict__ wa, float* __restrict__ out) {
  int idx = blockIdx.x * 256 + threadIdx.x;
  if (idx >= 12 * 196 * 49) return;
  int a = idx % 49; int n = (idx / 49) % 196; int h = idx / (49 * 196);
  int y = n / 14, x = n % 14;
  int y0, y1, x0, x1; float wy0, wy1, wx0, wx1;
  lin_w(y, y0, y1, wy0, wy1); lin_w(x, x0, x1, wx0, wx1);
  const float* p = na + (h * 49 + a) * 49;
  float v = wy0 * (wx0 * p[y0 * 7 + x0] + wx1 * p[y0 * 7 + x1])
          + wy1 * (wx0 * p[y1 * 7 + x0] + wx1 * p[y1 * 7 + x1]);
  v += ha[(h * 14 + y) * 49 + a] + wa[(h * 14 + x) * 49 + a];
  out[idx] = v;
}

// GEMM1: qkv[row][col] = sum_k X[row][k] * Wq[col][k]; M=100352 N=1152 K=384
// 128x128 block tile, 256 threads, 8x8 per thread, Kt=16. Output bf16.
__global__ __launch_bounds__(256) void k_gemm_qkv(const float* __restrict__ X,
    const float* __restrict__ Wt, u16* __restrict__ out) {
  __shared__ float As[16][132];
  __shared__ float Bs[16][132];
  const int tid = threadIdx.x;
  const int tx = tid & 15, ty = tid >> 4;
  const long row0 = (long)blockIdx.y * 128;
  const int col0 = blockIdx.x * 128;
  const int r = tid >> 2, q = tid & 3;
  const float* Ap = X + row0 * 384 + q * 4;
  const float* Bp = Wt + (long)col0 * 384 + q * 4;
  float acc[8][8] = {};
  for (int kt = 0; kt < 24; ++kt) {
    const int k0 = kt * 16;
    float4 a0 = *(const float4*)(Ap + (long)r * 384 + k0);
    float4 a1 = *(const float4*)(Ap + (long)(r + 64) * 384 + k0);
    float4 b0 = *(const float4*)(Bp + (long)r * 384 + k0);
    float4 b1 = *(const float4*)(Bp + (long)(r + 64) * 384 + k0);
    __syncthreads();
    As[q * 4 + 0][r] = a0.x; As[q * 4 + 1][r] = a0.y; As[q * 4 + 2][r] = a0.z; As[q * 4 + 3][r] = a0.w;
    As[q * 4 + 0][r + 64] = a1.x; As[q * 4 + 1][r + 64] = a1.y; As[q * 4 + 2][r + 64] = a1.z; As[q * 4 + 3][r + 64] = a1.w;
    Bs[q * 4 + 0][r] = b0.x; Bs[q * 4 + 1][r] = b0.y; Bs[q * 4 + 2][r] = b0.z; Bs[q * 4 + 3][r] = b0.w;
    Bs[q * 4 + 0][r + 64] = b1.x; Bs[q * 4 + 1][r + 64] = b1.y; Bs[q * 4 + 2][r + 64] = b1.z; Bs[q * 4 + 3][r + 64] = b1.w;
    __syncthreads();
#pragma unroll
    for (int k = 0; k < 16; ++k) {
      const float4 aA = *(const float4*)&As[k][ty * 8];
      const float4 aB = *(const float4*)&As[k][ty * 8 + 4];
      const float4 bA = *(const float4*)&Bs[k][tx * 8];
      const float4 bB = *(const float4*)&Bs[k][tx * 8 + 4];
      const float av[8] = {aA.x, aA.y, aA.z, aA.w, aB.x, aB.y, aB.z, aB.w};
      const float bv[8] = {bA.x, bA.y, bA.z, bA.w, bB.x, bB.y, bB.z, bB.w};
#pragma unroll
      for (int i = 0; i < 8; ++i)
#pragma unroll
        for (int j = 0; j < 8; ++j) acc[i][j] += av[i] * bv[j];
    }
  }
#pragma unroll
  for (int i = 0; i < 8; ++i) {
    long row = row0 + ty * 8 + i;
    union { u16 s[8]; uint4 v; } pk;
#pragma unroll
    for (int j = 0; j < 8; ++j) pk.s[j] = f2bf(acc[i][j]);
    *(uint4*)(out + row * 1152 + col0 + tx * 8) = pk.v;
  }
}

// agent[b][a][c] = 2x2 mean-pool of q (first 384 cols of qkv)
__global__ void k_agent_pool(const u16* __restrict__ qkv, float* __restrict__ agent) {
  int idx = blockIdx.x * 256 + threadIdx.x;
  if (idx >= 512 * 49 * 384) return;
  int c = idx % 384; int a = (idx / 384) % 49; int b = idx / (384 * 49);
  int ay = a / 7, ax = a % 7;
  int y0 = ay * 2, x0 = ax * 2;
  long base = (long)b * 196 * 1152 + c;
  float s = bf2f(qkv[base + (long)(y0 * 14 + x0) * 1152])
          + bf2f(qkv[base + (long)(y0 * 14 + x0 + 1) * 1152])
          + bf2f(qkv[base + (long)((y0 + 1) * 14 + x0) * 1152])
          + bf2f(qkv[base + (long)((y0 + 1) * 14 + x0 + 1) * 1152]);
  agent[idx] = 0.25f * s;
}

// agent attention: per (b,h), thread a: softmax_n(SCALE*ag.k + bias1) @ v -> agent_v[b,h,a,:]
__global__ __launch_bounds__(64) void k_agent_attn(const u16* __restrict__ qkv,
    const float* __restrict__ agent, const float* __restrict__ bias1,
    float* __restrict__ agent_v) {
  const int bh = blockIdx.x; const int b = bh / 12, h = bh % 12;
  const int a = threadIdx.x;
  const bool active = a < 49;
  const int aa = active ? a : 48;
  float ag[32];
  const float* agp = agent + ((long)(b * 49 + aa)) * 384 + h * 32;
#pragma unroll
  for (int d = 0; d < 32; ++d) ag[d] = agp[d] * SCALE;
  const float* b1 = bias1 + ((long)(h * 49 + aa)) * 196;
  const u16* kbase = qkv + (long)b * 196 * 1152 + 384 + h * 32;
  const u16* vbase = kbase + 384;
  float s = 0.f, acc[32] = {};
  for (int n = 0; n < 196; ++n) {
    const u16* kp = kbase + (long)n * 1152;
    float l = b1[n];
#pragma unroll
    for (int d = 0; d < 32; d += 2) {
      u32 kk = *(const u32*)(kp + d);
      l += ag[d] * bf2f((u16)(kk & 0xffff)) + ag[d + 1] * bf2f((u16)(kk >> 16));
    }
    float e = __expf(l);
    s += e;
    const u16* vp = vbase + (long)n * 1152;
#pragma unroll
    for (int d = 0; d < 32; d += 2) {
      u32 vv = *(const u32*)(vp + d);
      acc[d]     += e * bf2f((u16)(vv & 0xffff));
      acc[d + 1] += e * bf2f((u16)(vv >> 16));
    }
  }
  if (active) {
    float inv = 1.f / s;
    float* outp = agent_v + ((long)((b * 12 + h) * 49 + a)) * 32;
#pragma unroll
    for (int d = 0; d < 32; ++d) outp[d] = acc[d] * inv;
  }
}

// q attention: per (b,h), thread n: softmax_a(SCALE*q.ag + bias2) @ agent_v -> t[b,n,h*32:]
__global__ __launch_bounds__(256) void k_q_attn(const u16* __restrict__ qkv,
    const float* __restrict__ agent, const float* __restrict__ agent_v,
    const float* __restrict__ bias2, u16* __restrict__ t) {
  const int bh = blockIdx.x; const int b = bh / 12, h = bh % 12;
  const int n = threadIdx.x;
  if (n >= 196) return;
  float qd[32];
  const u16* qp = qkv + ((long)(b * 196 + n)) * 1152 + h * 32;
#pragma unroll
  for (int d = 0; d < 32; d += 2) {
    u32 qq = *(const u32*)(qp + d);
    qd[d]     = bf2f((u16)(qq & 0xffff)) * SCALE;
    qd[d + 1] = bf2f((u16)(qq >> 16)) * SCALE;
  }
  const float* b2 = bias2 + ((long)(h * 196 + n)) * 49;
  float s = 0.f, acc[32] = {};
  for (int a = 0; a < 49; ++a) {
    const float* agp = agent + ((long)(b * 49 + a)) * 384 + h * 32;
    float l = b2[a];
#pragma unroll
    for (int d = 0; d < 32; ++d) l += qd[d] * agp[d];
    float e = __expf(l);
    s += e;
    const float* av = agent_v + ((long)((b * 12 + h) * 49 + a)) * 32;
#pragma unroll
    for (int d = 0; d < 32; ++d) acc[d] += e * av[d];
  }
  float inv = 1.f / s;
  u16* tp = t + ((long)(b * 196 + n)) * 384 + h * 32;
#pragma unroll
  for (int d = 0; d < 32; d += 2) {
    u32 pk = (u32)f2bf(acc[d] * inv) | ((u32)f2bf(acc[d + 1] * inv) << 16);
    *(u32*)(tp + d) = pk;
  }
}

// depthwise 3x3 conv over v (cols 768.. of qkv), accumulate into t
__global__ void k_dwc(const u16* __restrict__ qkv, const float* __restrict__ w,
                      const float* __restrict__ bias, u16* __restrict__ t) {
  long idx = (long)blockIdx.x * 256 + threadIdx.x;
  if (idx >= (long)512 * 196 * 384) return;
  int c = (int)(idx % 384); long bn = idx / 384; int n = (int)(bn % 196); int b = (int)(bn / 196);
  int y = n / 14, x = n % 14;
  float sum = bias[c];
  const float* wc = w + c * 9;
#pragma unroll
  for (int dy = -1; dy <= 1; ++dy) {
    int yy = y + dy;
    if (yy < 0 || yy > 13) continue;
#pragma unroll
    for (int dx = -1; dx <= 1; ++dx) {
      int xx = x + dx;
      if (xx < 0 || xx > 13) continue;
      float v = bf2f(qkv[((long)(b * 196 + yy * 14 + xx)) * 1152 + 768 + c]);
      sum += v * wc[(dy + 1) * 3 + (dx + 1)];
    }
  }
  t[idx] = f2bf(bf2f(t[idx]) + sum);
}

// GEMMF: out[row][col] = sum_k t[row][k]*Wp[col][k] + pb[col]; M=100352 N=384 K=384
__global__ __launch_bounds__(256) void k_gemm_out(const u16* __restrict__ T,
    const float* __restrict__ Wt, const float* __restrict__ pb, float* __restrict__ out) {
  __shared__ float As[16][132];
  __shared__ float Bs[16][132];
  const int tid = threadIdx.x;
  const int tx = tid & 15, ty = tid >> 4;
  const long row0 = (long)blockIdx.y * 128;
  const int col0 = blockIdx.x * 128;
  const int rA = tid >> 1, qA = tid & 1;
  const int r = tid >> 2, q = tid & 3;
  const u16* Ap = T + row0 * 384 + qA * 8;
  const float* Bp = Wt + (long)col0 * 384 + q * 4;
  float acc[8][8] = {};
  for (int kt = 0; kt < 24; ++kt) {
    const int k0 = kt * 16;
    uint4 au = *(const uint4*)(Ap + (long)rA * 384 + k0);
    float4 b0 = *(const float4*)(Bp + (long)r * 384 + k0);
    float4 b1 = *(const float4*)(Bp + (long)(r + 64) * 384 + k0);
    __syncthreads();
    const u32 aw[4] = {au.x, au.y, au.z, au.w};
#pragma unroll
    for (int j = 0; j < 4; ++j) {
      As[qA * 8 + 2 * j    ][rA] = bf2f((u16)(aw[j] & 0xffff));
      As[qA * 8 + 2 * j + 1][rA] = bf2f((u16)(aw[j] >> 16));
    }
    Bs[q * 4 + 0][r] = b0.x; Bs[q * 4 + 1][r] = b0.y; Bs[q * 4 + 2][r] = b0.z; Bs[q * 4 + 3][r] = b0.w;
    Bs[q * 4 + 0][r + 64] = b1.x; Bs[q * 4 + 1][r + 64] = b1.y; Bs[q * 4 + 2][r + 64] = b1.z; Bs[q * 4 + 3][r + 64] = b1.w;
    __syncthreads();
#pragma unroll
    for (int k = 0; k < 16; ++k) {
      const float4 aA = *(const float4*)&As[k][ty * 8];
      const float4 aB = *(const float4*)&As[k][ty * 8 + 4];
      const float4 bA = *(const float4*)&Bs[k][tx * 8];
      const float4 bB = *(const float4*)&Bs[k][tx * 8 + 4];
      const float av[8] = {aA.x, aA.y, aA.z, aA.w, aB.x, aB.y, aB.z, aB.w};
      const float bv[8] = {bA.x, bA.y, bA.z, bA.w, bB.x, bB.y, bB.z, bB.w};
#pragma unroll
      for (int i = 0; i < 8; ++i)
#pragma unroll
        for (int j = 0; j < 8; ++j) acc[i][j] += av[i] * bv[j];
    }
  }
  float pbv[8];
#pragma unroll
  for (int j = 0; j < 8; ++j) pbv[j] = pb[col0 + tx * 8 + j];
#pragma unroll
  for (int i = 0; i < 8; ++i) {
    long row = row0 + ty * 8 + i;
    float4 o0 = make_float4(acc[i][0] + pbv[0], acc[i][1] + pbv[1], acc[i][2] + pbv[2], acc[i][3] + pbv[3]);
    float4 o1 = make_float4(acc[i][4] + pbv[4], acc[i][5] + pbv[5], acc[i][6] + pbv[6], acc[i][7] + pbv[7]);
    float* op = out + row * 384 + col0 + tx * 8;
    *(float4*)op = o0;
    *(float4*)(op + 4) = o1;
  }
}

extern "C" void kernel_launch(void* const* d_in, const int* in_sizes, int n_in,
                              void* d_out, int out_size, void* d_ws, size_t ws_size,
                              hipStream_t stream) {
  (void)in_sizes; (void)n_in; (void)out_size; (void)ws_size;
  const float* x      = (const float*)d_in[0];
  const float* qkv_w  = (const float*)d_in[1];
  const float* proj_w = (const float*)d_in[2];
  const float* proj_b = (const float*)d_in[3];
  const float* dwc_w  = (const float*)d_in[4];
  const float* dwc_b  = (const float*)d_in[5];
  const float* an_b   = (const float*)d_in[6];
  const float* ah_b   = (const float*)d_in[7];
  const float* aw_b   = (const float*)d_in[8];
  const float* na_b   = (const float*)d_in[9];
  const float* ha_b   = (const float*)d_in[10];
  const float* wa_b   = (const float*)d_in[11];
  float* out = (float*)d_out;

  // workspace layout (bytes): needs ~386.3 MB
  char* ws = (char*)d_ws;
  u16*   qkv     = (u16*)ws;                          // 100352*1152 bf16 = 231,211,008 B
  u16*   t       = (u16*)(ws + 231211008);            // 100352*384 bf16  =  77,070,336 B
  float* agent   = (float*)(ws + 308281344);          // 512*49*384 f32   =  38,535,168 B
  float* agent_v = (float*)(ws + 346816512);          // 512*12*49*32 f32 =  38,535,168 B
  float* bias1   = (float*)(ws + 385351680);          // 12*49*196 f32
  float* bias2   = (float*)(ws + 385812672);          // 12*196*49 f32

  k_bias1<<<451, 256, 0, stream>>>(an_b, ah_b, aw_b, bias1);
  k_bias2<<<451, 256, 0, stream>>>(na_b, ha_b, wa_b, bias2);
  k_gemm_qkv<<<dim3(9, 784), 256, 0, stream>>>(x, qkv_w, qkv);
  k_agent_pool<<<37632, 256, 0, stream>>>(qkv, agent);
  k_agent_attn<<<6144, 64, 0, stream>>>(qkv, agent, bias1, agent_v);
  k_q_attn<<<6144, 256, 0, stream>>>(qkv, agent, agent_v, bias2, t);
  k_dwc<<<150528, 256, 0, stream>>>(qkv, dwc_w, dwc_b, t);
  k_gemm_out<<<dim3(3, 784), 256, 0, stream>>>(t, proj_w, proj_b, out);
}

// Round 2
// 1320.711 us; speedup vs baseline: 1.7920x; 1.7920x over previous
//
#include <hip/hip_runtime.h>

typedef unsigned short u16;
typedef unsigned int   u32;

// B=512 N=196 C=384 H=12 D=32 A=49 W=14, 3C=1152
#define SCALE 0.17677669529663687f

using short8 = __attribute__((ext_vector_type(8))) short;
using bf16x8 = __attribute__((ext_vector_type(8))) __bf16;
using f32x4  = __attribute__((ext_vector_type(4))) float;

__device__ __forceinline__ float bf2f(u16 u) {
  union { u32 i; float f; } c; c.i = ((u32)u) << 16; return c.f;
}
__device__ __forceinline__ u16 f2bf(float f) {
  union { float f; u32 i; } c; c.f = f;
  u32 x = c.i;
  return (u16)((x + 0x7fffu + ((x >> 16) & 1u)) >> 16);
}

// async global->LDS, 16B per lane. LDS dest is wave-uniform base + lane*16.
__device__ __forceinline__ void gl_lds16(const void* g, void* l) {
  __builtin_amdgcn_global_load_lds(
      (__attribute__((address_space(1))) void*)(uintptr_t)g,
      (__attribute__((address_space(3))) void*)(uintptr_t)l, 16, 0, 0);
}

// ---------------- bias precompute ----------------
__device__ __forceinline__ void lin_w(int i, int& i0, int& i1, float& w0, float& w1) {
  if (i == 0)       { i0 = 0; i1 = 0; w0 = 1.f;  w1 = 0.f;  }
  else if (i == 13) { i0 = 6; i1 = 6; w0 = 1.f;  w1 = 0.f;  }
  else if (i & 1)   { int j = i >> 1; i0 = j;     i1 = j + 1; w0 = 0.75f; w1 = 0.25f; }
  else              { int j = i >> 1; i0 = j - 1; i1 = j;     w0 = 0.25f; w1 = 0.75f; }
}

__global__ void k_bias1(const float* __restrict__ an, const float* __restrict__ ah,
                        const float* __restrict__ aw, float* __restrict__ out) {
  int idx = blockIdx.x * 256 + threadIdx.x;
  if (idx >= 12 * 49 * 196) return;
  int n = idx % 196; int a = (idx / 196) % 49; int h = idx / (196 * 49);
  int y = n / 14, x = n % 14;
  int y0, y1, x0, x1; float wy0, wy1, wx0, wx1;
  lin_w(y, y0, y1, wy0, wy1); lin_w(x, x0, x1, wx0, wx1);
  const float* p = an + (h * 49 + a) * 49;
  float v = wy0 * (wx0 * p[y0 * 7 + x0] + wx1 * p[y0 * 7 + x1])
          + wy1 * (wx0 * p[y1 * 7 + x0] + wx1 * p[y1 * 7 + x1]);
  v += ah[(h * 49 + a) * 14 + y] + aw[(h * 49 + a) * 14 + x];
  out[idx] = v;
}

__global__ void k_bias2(const float* __restrict__ na, const float* __restrict__ ha,
                        const float* __restrict__ wa, float* __restrict__ out) {
  int idx = blockIdx.x * 256 + threadIdx.x;
  if (idx >= 12 * 196 * 49) return;
  int a = idx % 49; int n = (idx / 49) % 196; int h = idx / (49 * 196);
  int y = n / 14, x = n % 14;
  int y0, y1, x0, x1; float wy0, wy1, wx0, wx1;
  lin_w(y, y0, y1, wy0, wy1); lin_w(x, x0, x1, wx0, wx1);
  const float* p = na + (h * 49 + a) * 49;
  float v = wy0 * (wx0 * p[y0 * 7 + x0] + wx1 * p[y0 * 7 + x1])
          + wy1 * (wx0 * p[y1 * 7 + x0] + wx1 * p[y1 * 7 + x1]);
  v += ha[(h * 14 + y) * 49 + a] + wa[(h * 14 + x) * 49 + a];
  out[idx] = v;
}

// ---------------- fp32 -> bf16 conversion ----------------
__global__ void k_f2bf(const float* __restrict__ src, u16* __restrict__ dst, long n) {
  long i = ((long)blockIdx.x * 256 + threadIdx.x) * 8;
  if (i >= n) return;
  float4 a = *(const float4*)(src + i);
  float4 b = *(const float4*)(src + i + 4);
  union { u16 s[8]; uint4 v; } pk;
  pk.s[0] = f2bf(a.x); pk.s[1] = f2bf(a.y); pk.s[2] = f2bf(a.z); pk.s[3] = f2bf(a.w);
  pk.s[4] = f2bf(b.x); pk.s[5] = f2bf(b.y); pk.s[6] = f2bf(b.z); pk.s[7] = f2bf(b.w);
  *(uint4*)(dst + i) = pk.v;
}

// ---------------- MFMA GEMM: qkv = xb @ wqkv^T (bf16 out) ----------------
// M=100352 N=1152 K=384. 128x128 tile, BK=64, 4 waves (2x2), 4x4 frags of 16x16x32.
__global__ __launch_bounds__(256) void k_mfma_qkv(const u16* __restrict__ A,
    const u16* __restrict__ Bw, u16* __restrict__ out) {
  __shared__ __align__(16) u16 As[128 * 64];
  __shared__ __align__(16) u16 Bs[128 * 64];
  const int tid = threadIdx.x;
  const int lane = tid & 63, w = tid >> 6;
  const int wm = (w >> 1) * 64, wn = (w & 1) * 64;
  const long row0 = (long)blockIdx.y * 128;
  const int col0 = blockIdx.x * 128;
  const int quad = lane >> 4, m16 = lane & 15;
  f32x4 acc[4][4] = {};
  for (int kt = 0; kt < 6; ++kt) {
    const int k0 = kt * 64;
    __syncthreads();  // all waves done reading LDS from prev iter
#pragma unroll
    for (int i = 0; i < 4; ++i) {
      int c = i * 256 + w * 64 + lane;              // 16B chunk id, 0..1023
      const u16* ga = A + (row0 + (c >> 3)) * 384 + k0 + (c & 7) * 8;
      gl_lds16(ga, &As[(i * 256 + w * 64) * 8]);
      const u16* gb = Bw + (long)(col0 + (c >> 3)) * 384 + k0 + (c & 7) * 8;
      gl_lds16(gb, &Bs[(i * 256 + w * 64) * 8]);
    }
    __syncthreads();  // vmcnt(0) drain + barrier: tile ready
#pragma unroll
    for (int kk = 0; kk < 2; ++kk) {
      bf16x8 av[4], bv[4];
#pragma unroll
      for (int i = 0; i < 4; ++i)
        av[i] = *(const bf16x8*)&As[(wm + i * 16 + m16) * 64 + kk * 32 + quad * 8];
#pragma unroll
      for (int j = 0; j < 4; ++j)
        bv[j] = *(const bf16x8*)&Bs[(wn + j * 16 + m16) * 64 + kk * 32 + quad * 8];
#pragma unroll
      for (int i = 0; i < 4; ++i)
#pragma unroll
        for (int j = 0; j < 4; ++j)
          acc[i][j] = __builtin_amdgcn_mfma_f32_16x16x32_bf16(av[i], bv[j], acc[i][j], 0, 0, 0);
    }
  }
#pragma unroll
  for (int i = 0; i < 4; ++i)
#pragma unroll
    for (int r = 0; r < 4; ++r) {
      long row = row0 + wm + i * 16 + quad * 4 + r;
      u16* op = out + row * 1152 + col0 + wn + m16;
#pragma unroll
      for (int j = 0; j < 4; ++j) op[j * 16] = f2bf(acc[i][j][r]);
    }
}

// ---------------- MFMA GEMM: out = t @ proj^T + pb (fp32 out) ----------------
// M=100352 N=384 K=384
__global__ __launch_bounds__(256) void k_mfma_out(const u16* __restrict__ A,
    const u16* __restrict__ Bw, const float* __restrict__ pb, float* __restrict__ out) {
  __shared__ __align__(16) u16 As[128 * 64];
  __shared__ __align__(16) u16 Bs[128 * 64];
  const int tid = threadIdx.x;
  const int lane = tid & 63, w = tid >> 6;
  const int wm = (w >> 1) * 64, wn = (w & 1) * 64;
  const long row0 = (long)blockIdx.y * 128;
  const int col0 = blockIdx.x * 128;
  const int quad = lane >> 4, m16 = lane & 15;
  f32x4 acc[4][4] = {};
  for (int kt = 0; kt < 6; ++kt) {
    const int k0 = kt * 64;
    __syncthreads();
#pragma unroll
    for (int i = 0; i < 4; ++i) {
      int c = i * 256 + w * 64 + lane;
      const u16* ga = A + (row0 + (c >> 3)) * 384 + k0 + (c & 7) * 8;
      gl_lds16(ga, &As[(i * 256 + w * 64) * 8]);
      const u16* gb = Bw + (long)(col0 + (c >> 3)) * 384 + k0 + (c & 7) * 8;
      gl_lds16(gb, &Bs[(i * 256 + w * 64) * 8]);
    }
    __syncthreads();
#pragma unroll
    for (int kk = 0; kk < 2; ++kk) {
      bf16x8 av[4], bv[4];
#pragma unroll
      for (int i = 0; i < 4; ++i)
        av[i] = *(const bf16x8*)&As[(wm + i * 16 + m16) * 64 + kk * 32 + quad * 8];
#pragma unroll
      for (int j = 0; j < 4; ++j)
        bv[j] = *(const bf16x8*)&Bs[(wn + j * 16 + m16) * 64 + kk * 32 + quad * 8];
#pragma unroll
      for (int i = 0; i < 4; ++i)
#pragma unroll
        for (int j = 0; j < 4; ++j)
          acc[i][j] = __builtin_amdgcn_mfma_f32_16x16x32_bf16(av[i], bv[j], acc[i][j], 0, 0, 0);
    }
  }
  float pbv[4];
#pragma unroll
  for (int j = 0; j < 4; ++j) pbv[j] = pb[col0 + wn + j * 16 + m16];
#pragma unroll
  for (int i = 0; i < 4; ++i)
#pragma unroll
    for (int r = 0; r < 4; ++r) {
      long row = row0 + wm + i * 16 + quad * 4 + r;
      float* op = out + row * 384 + col0 + wn + m16;
#pragma unroll
      for (int j = 0; j < 4; ++j) op[j * 16] = acc[i][j][r] + pbv[j];
    }
}

// ---------------- agent pooling ----------------
__global__ void k_agent_pool(const u16* __restrict__ qkv, float* __restrict__ agent) {
  int idx = blockIdx.x * 256 + threadIdx.x;
  if (idx >= 512 * 49 * 384) return;
  int c = idx % 384; int a = (idx / 384) % 49; int b = idx / (384 * 49);
  int ay = a / 7, ax = a % 7;
  int y0 = ay * 2, x0 = ax * 2;
  long base = (long)b * 196 * 1152 + c;
  float s = bf2f(qkv[base + (long)(y0 * 14 + x0) * 1152])
          + bf2f(qkv[base + (long)(y0 * 14 + x0 + 1) * 1152])
          + bf2f(qkv[base + (long)((y0 + 1) * 14 + x0) * 1152])
          + bf2f(qkv[base + (long)((y0 + 1) * 14 + x0 + 1) * 1152]);
  agent[idx] = 0.25f * s;
}

// ---------------- agent attention ----------------
__global__ __launch_bounds__(64) void k_agent_attn(const u16* __restrict__ qkv,
    const float* __restrict__ agent, const float* __restrict__ bias1,
    float* __restrict__ agent_v) {
  const int bh = blockIdx.x; const int b = bh / 12, h = bh % 12;
  const int a = threadIdx.x;
  const bool active = a < 49;
  const int aa = active ? a : 48;
  float ag[32];
  const float* agp = agent + ((long)(b * 49 + aa)) * 384 + h * 32;
#pragma unroll
  for (int d = 0; d < 32; ++d) ag[d] = agp[d] * SCALE;
  const float* b1 = bias1 + ((long)(h * 49 + aa)) * 196;
  const u16* kbase = qkv + (long)b * 196 * 1152 + 384 + h * 32;
  const u16* vbase = kbase + 384;
  float s = 0.f, acc[32] = {};
  for (int n = 0; n < 196; ++n) {
    const u16* kp = kbase + (long)n * 1152;
    float l = b1[n];
#pragma unroll
    for (int d = 0; d < 32; d += 2) {
      u32 kk = *(const u32*)(kp + d);
      l += ag[d] * bf2f((u16)(kk & 0xffff)) + ag[d + 1] * bf2f((u16)(kk >> 16));
    }
    float e = __expf(l);
    s += e;
    const u16* vp = vbase + (long)n * 1152;
#pragma unroll
    for (int d = 0; d < 32; d += 2) {
      u32 vv = *(const u32*)(vp + d);
      acc[d]     += e * bf2f((u16)(vv & 0xffff));
      acc[d + 1] += e * bf2f((u16)(vv >> 16));
    }
  }
  if (active) {
    float inv = 1.f / s;
    float* outp = agent_v + ((long)((b * 12 + h) * 49 + a)) * 32;
#pragma unroll
    for (int d = 0; d < 32; ++d) outp[d] = acc[d] * inv;
  }
}

// ---------------- q attention ----------------
__global__ __launch_bounds__(256) void k_q_attn(const u16* __restrict__ qkv,
    const float* __restrict__ agent, const float* __restrict__ agent_v,
    const float* __restrict__ bias2, u16* __restrict__ t) {
  const int bh = blockIdx.x; const int b = bh / 12, h = bh % 12;
  const int n = threadIdx.x;
  if (n >= 196) return;
  float qd[32];
  const u16* qp = qkv + ((long)(b * 196 + n)) * 1152 + h * 32;
#pragma unroll
  for (int d = 0; d < 32; d += 2) {
    u32 qq = *(const u32*)(qp + d);
    qd[d]     = bf2f((u16)(qq & 0xffff)) * SCALE;
    qd[d + 1] = bf2f((u16)(qq >> 16)) * SCALE;
  }
  const float* b2 = bias2 + ((long)(h * 196 + n)) * 49;
  float s = 0.f, acc[32] = {};
  for (int a = 0; a < 49; ++a) {
    const float* agp = agent + ((long)(b * 49 + a)) * 384 + h * 32;
    float l = b2[a];
#pragma unroll
    for (int d = 0; d < 32; ++d) l += qd[d] * agp[d];
    float e = __expf(l);
    s += e;
    const float* av = agent_v + ((long)((b * 12 + h) * 49 + a)) * 32;
#pragma unroll
    for (int d = 0; d < 32; ++d) acc[d] += e * av[d];
  }
  float inv = 1.f / s;
  u16* tp = t + ((long)(b * 196 + n)) * 384 + h * 32;
#pragma unroll
  for (int d = 0; d < 32; d += 2) {
    u32 pk = (u32)f2bf(acc[d] * inv) | ((u32)f2bf(acc[d + 1] * inv) << 16);
    *(u32*)(tp + d) = pk;
  }
}

// ---------------- depthwise 3x3 conv, accumulate into t ----------------
__global__ void k_dwc(const u16* __restrict__ qkv, const float* __restrict__ w,
                      const float* __restrict__ bias, u16* __restrict__ t) {
  long idx = (long)blockIdx.x * 256 + threadIdx.x;
  if (idx >= (long)512 * 196 * 384) return;
  int c = (int)(idx % 384); long bn = idx / 384; int n = (int)(bn % 196); int b = (int)(bn / 196);
  int y = n / 14, x = n % 14;
  float sum = bias[c];
  const float* wc = w + c * 9;
#pragma unroll
  for (int dy = -1; dy <= 1; ++dy) {
    int yy = y + dy;
    if (yy < 0 || yy > 13) continue;
#pragma unroll
    for (int dx = -1; dx <= 1; ++dx) {
      int xx = x + dx;
      if (xx < 0 || xx > 13) continue;
      float v = bf2f(qkv[((long)(b * 196 + yy * 14 + xx)) * 1152 + 768 + c]);
      sum += v * wc[(dy + 1) * 3 + (dx + 1)];
    }
  }
  t[idx] = f2bf(bf2f(t[idx]) + sum);
}

extern "C" void kernel_launch(void* const* d_in, const int* in_sizes, int n_in,
                              void* d_out, int out_size, void* d_ws, size_t ws_size,
                              hipStream_t stream) {
  (void)in_sizes; (void)n_in; (void)out_size; (void)ws_size;
  const float* x      = (const float*)d_in[0];
  const float* qkv_w  = (const float*)d_in[1];
  const float* proj_w = (const float*)d_in[2];
  const float* proj_b = (const float*)d_in[3];
  const float* dwc_w  = (const float*)d_in[4];
  const float* dwc_b  = (const float*)d_in[5];
  const float* an_b   = (const float*)d_in[6];
  const float* ah_b   = (const float*)d_in[7];
  const float* aw_b   = (const float*)d_in[8];
  const float* na_b   = (const float*)d_in[9];
  const float* ha_b   = (const float*)d_in[10];
  const float* wa_b   = (const float*)d_in[11];
  float* out = (float*)d_out;

  // workspace layout (bytes), ~387.5 MB total:
  char* ws = (char*)d_ws;
  u16*   qkv     = (u16*)ws;                       // 231,211,008
  u16*   t       = (u16*)(ws + 231211008);         //  77,070,336
  u16*   xb      = (u16*)(ws + 308281344);         //  77,070,336 (dead after k_mfma_qkv)
  float* agent   = (float*)(ws + 308281344);       //  38,535,168 (overlays xb, written after)
  float* agent_v = (float*)(ws + 346816512);       //  38,535,168 (overlays xb, written after)
  u16*   wqkvb   = (u16*)(ws + 385351680);         //     884,736
  u16*   wprojb  = (u16*)(ws + 386236416);         //     294,912
  float* bias1   = (float*)(ws + 386531328);       //     460,992
  float* bias2   = (float*)(ws + 386992320);       //     460,992

  k_bias1<<<451, 256, 0, stream>>>(an_b, ah_b, aw_b, bias1);
  k_bias2<<<451, 256, 0, stream>>>(na_b, ha_b, wa_b, bias2);
  k_f2bf<<<18816, 256, 0, stream>>>(x, xb, (long)100352 * 384);
  k_f2bf<<<216, 256, 0, stream>>>(qkv_w, wqkvb, (long)1152 * 384);
  k_f2bf<<<72, 256, 0, stream>>>(proj_w, wprojb, (long)384 * 384);
  k_mfma_qkv<<<dim3(9, 784), 256, 0, stream>>>(xb, wqkvb, qkv);
  k_agent_pool<<<37632, 256, 0, stream>>>(qkv, agent);
  k_agent_attn<<<6144, 64, 0, stream>>>(qkv, agent, bias1, agent_v);
  k_q_attn<<<6144, 256, 0, stream>>>(qkv, agent, agent_v, bias2, t);
  k_dwc<<<150528, 256, 0, stream>>>(qkv, dwc_w, dwc_b, t);
  k_mfma_out<<<dim3(3, 784), 256, 0, stream>>>(t, proj_w != nullptr ? wprojb : wprojb, proj_b, out);
}

// Round 3
// 993.845 us; speedup vs baseline: 2.3814x; 1.3289x over previous
//
#include <hip/hip_runtime.h>

typedef unsigned short u16;
typedef unsigned int   u32;

// B=512 N=196 C=384 H=12 D=32 A=49 W=14, 3C=1152
#define SCALE 0.17677669529663687f

using bf16x8 = __attribute__((ext_vector_type(8))) __bf16;
using f32x4  = __attribute__((ext_vector_type(4))) float;

__device__ __forceinline__ float bf2f(u16 u) {
  union { u32 i; float f; } c; c.i = ((u32)u) << 16; return c.f;
}
__device__ __forceinline__ u16 f2bf(float f) {
  union { float f; u32 i; } c; c.f = f;
  u32 x = c.i;
  return (u16)((x + 0x7fffu + ((x >> 16) & 1u)) >> 16);
}

// async global->LDS, 16B per lane (GEMM staging)
__device__ __forceinline__ void gl_lds16(const void* g, void* l) {
  __builtin_amdgcn_global_load_lds(
      (__attribute__((address_space(1))) void*)(uintptr_t)g,
      (__attribute__((address_space(3))) void*)(uintptr_t)l, 16, 0, 0);
}

// 16B LDS fragment load via two 8B reads (rows are 8B- but not 16B-aligned)
__device__ __forceinline__ bf16x8 lds8(const u16* p) {
  union { bf16x8 v; uint2 u[2]; } r;
  r.u[0] = *(const uint2*)p;
  r.u[1] = *(const uint2*)(p + 4);
  return r.v;
}

// ---------------- bias precompute ----------------
__device__ __forceinline__ void lin_w(int i, int& i0, int& i1, float& w0, float& w1) {
  if (i == 0)       { i0 = 0; i1 = 0; w0 = 1.f;  w1 = 0.f;  }
  else if (i == 13) { i0 = 6; i1 = 6; w0 = 1.f;  w1 = 0.f;  }
  else if (i & 1)   { int j = i >> 1; i0 = j;     i1 = j + 1; w0 = 0.75f; w1 = 0.25f; }
  else              { int j = i >> 1; i0 = j - 1; i1 = j;     w0 = 0.25f; w1 = 0.75f; }
}

__global__ void k_bias1(const float* __restrict__ an, const float* __restrict__ ah,
                        const float* __restrict__ aw, float* __restrict__ out) {
  int idx = blockIdx.x * 256 + threadIdx.x;
  if (idx >= 12 * 49 * 196) return;
  int n = idx % 196; int a = (idx / 196) % 49; int h = idx / (196 * 49);
  int y = n / 14, x = n % 14;
  int y0, y1, x0, x1; float wy0, wy1, wx0, wx1;
  lin_w(y, y0, y1, wy0, wy1); lin_w(x, x0, x1, wx0, wx1);
  const float* p = an + (h * 49 + a) * 49;
  float v = wy0 * (wx0 * p[y0 * 7 + x0] + wx1 * p[y0 * 7 + x1])
          + wy1 * (wx0 * p[y1 * 7 + x0] + wx1 * p[y1 * 7 + x1]);
  v += ah[(h * 49 + a) * 14 + y] + aw[(h * 49 + a) * 14 + x];
  out[idx] = v;
}

__global__ void k_bias2(const float* __restrict__ na, const float* __restrict__ ha,
                        const float* __restrict__ wa, float* __restrict__ out) {
  int idx = blockIdx.x * 256 + threadIdx.x;
  if (idx >= 12 * 196 * 49) return;
  int a = idx % 49; int n = (idx / 49) % 196; int h = idx / (49 * 196);
  int y = n / 14, x = n % 14;
  int y0, y1, x0, x1; float wy0, wy1, wx0, wx1;
  lin_w(y, y0, y1, wy0, wy1); lin_w(x, x0, x1, wx0, wx1);
  const float* p = na + (h * 49 + a) * 49;
  float v = wy0 * (wx0 * p[y0 * 7 + x0] + wx1 * p[y0 * 7 + x1])
          + wy1 * (wx0 * p[y1 * 7 + x0] + wx1 * p[y1 * 7 + x1]);
  v += ha[(h * 14 + y) * 49 + a] + wa[(h * 14 + x) * 49 + a];
  out[idx] = v;
}

// ---------------- fp32 -> bf16 conversion ----------------
__global__ void k_f2bf(const float* __restrict__ src, u16* __restrict__ dst, long n) {
  long i = ((long)blockIdx.x * 256 + threadIdx.x) * 8;
  if (i >= n) return;
  float4 a = *(const float4*)(src + i);
  float4 b = *(const float4*)(src + i + 4);
  union { u16 s[8]; uint4 v; } pk;
  pk.s[0] = f2bf(a.x); pk.s[1] = f2bf(a.y); pk.s[2] = f2bf(a.z); pk.s[3] = f2bf(a.w);
  pk.s[4] = f2bf(b.x); pk.s[5] = f2bf(b.y); pk.s[6] = f2bf(b.z); pk.s[7] = f2bf(b.w);
  *(uint4*)(dst + i) = pk.v;
}

// ---------------- MFMA GEMM: qkv = xb @ wqkv^T (bf16 out) ----------------
__global__ __launch_bounds__(256) void k_mfma_qkv(const u16* __restrict__ A,
    const u16* __restrict__ Bw, u16* __restrict__ out) {
  __shared__ __align__(16) u16 As[128 * 64];
  __shared__ __align__(16) u16 Bs[128 * 64];
  const int tid = threadIdx.x;
  const int lane = tid & 63, w = tid >> 6;
  const int wm = (w >> 1) * 64, wn = (w & 1) * 64;
  const long row0 = (long)blockIdx.y * 128;
  const int col0 = blockIdx.x * 128;
  const int quad = lane >> 4, m16 = lane & 15;
  f32x4 acc[4][4] = {};
  for (int kt = 0; kt < 6; ++kt) {
    const int k0 = kt * 64;
    __syncthreads();
#pragma unroll
    for (int i = 0; i < 4; ++i) {
      int c = i * 256 + w * 64 + lane;
      const u16* ga = A + (row0 + (c >> 3)) * 384 + k0 + (c & 7) * 8;
      gl_lds16(ga, &As[(i * 256 + w * 64) * 8]);
      const u16* gb = Bw + (long)(col0 + (c >> 3)) * 384 + k0 + (c & 7) * 8;
      gl_lds16(gb, &Bs[(i * 256 + w * 64) * 8]);
    }
    __syncthreads();
#pragma unroll
    for (int kk = 0; kk < 2; ++kk) {
      bf16x8 av[4], bv[4];
#pragma unroll
      for (int i = 0; i < 4; ++i)
        av[i] = *(const bf16x8*)&As[(wm + i * 16 + m16) * 64 + kk * 32 + quad * 8];
#pragma unroll
      for (int j = 0; j < 4; ++j)
        bv[j] = *(const bf16x8*)&Bs[(wn + j * 16 + m16) * 64 + kk * 32 + quad * 8];
#pragma unroll
      for (int i = 0; i < 4; ++i)
#pragma unroll
        for (int j = 0; j < 4; ++j)
          acc[i][j] = __builtin_amdgcn_mfma_f32_16x16x32_bf16(av[i], bv[j], acc[i][j], 0, 0, 0);
    }
  }
#pragma unroll
  for (int i = 0; i < 4; ++i)
#pragma unroll
    for (int r = 0; r < 4; ++r) {
      long row = row0 + wm + i * 16 + quad * 4 + r;
      u16* op = out + row * 1152 + col0 + wn + m16;
#pragma unroll
      for (int j = 0; j < 4; ++j) op[j * 16] = f2bf(acc[i][j][r]);
    }
}

// ---------------- MFMA GEMM: out = t @ proj^T + pb (fp32 out) ----------------
__global__ __launch_bounds__(256) void k_mfma_out(const u16* __restrict__ A,
    const u16* __restrict__ Bw, const float* __restrict__ pb, float* __restrict__ out) {
  __shared__ __align__(16) u16 As[128 * 64];
  __shared__ __align__(16) u16 Bs[128 * 64];
  const int tid = threadIdx.x;
  const int lane = tid & 63, w = tid >> 6;
  const int wm = (w >> 1) * 64, wn = (w & 1) * 64;
  const long row0 = (long)blockIdx.y * 128;
  const int col0 = blockIdx.x * 128;
  const int quad = lane >> 4, m16 = lane & 15;
  f32x4 acc[4][4] = {};
  for (int kt = 0; kt < 6; ++kt) {
    const int k0 = kt * 64;
    __syncthreads();
#pragma unroll
    for (int i = 0; i < 4; ++i) {
      int c = i * 256 + w * 64 + lane;
      const u16* ga = A + (row0 + (c >> 3)) * 384 + k0 + (c & 7) * 8;
      gl_lds16(ga, &As[(i * 256 + w * 64) * 8]);
      const u16* gb = Bw + (long)(col0 + (c >> 3)) * 384 + k0 + (c & 7) * 8;
      gl_lds16(gb, &Bs[(i * 256 + w * 64) * 8]);
    }
    __syncthreads();
#pragma unroll
    for (int kk = 0; kk < 2; ++kk) {
      bf16x8 av[4], bv[4];
#pragma unroll
      for (int i = 0; i < 4; ++i)
        av[i] = *(const bf16x8*)&As[(wm + i * 16 + m16) * 64 + kk * 32 + quad * 8];
#pragma unroll
      for (int j = 0; j < 4; ++j)
        bv[j] = *(const bf16x8*)&Bs[(wn + j * 16 + m16) * 64 + kk * 32 + quad * 8];
#pragma unroll
      for (int i = 0; i < 4; ++i)
#pragma unroll
        for (int j = 0; j < 4; ++j)
          acc[i][j] = __builtin_amdgcn_mfma_f32_16x16x32_bf16(av[i], bv[j], acc[i][j], 0, 0, 0);
    }
  }
  float pbv[4];
#pragma unroll
  for (int j = 0; j < 4; ++j) pbv[j] = pb[col0 + wn + j * 16 + m16];
#pragma unroll
  for (int i = 0; i < 4; ++i)
#pragma unroll
    for (int r = 0; r < 4; ++r) {
      long row = row0 + wm + i * 16 + quad * 4 + r;
      float* op = out + row * 384 + col0 + wn + m16;
#pragma unroll
      for (int j = 0; j < 4; ++j) op[j * 16] = acc[i][j][r] + pbv[j];
    }
}

// ---------------- fused pool + agent-attn + q-attn + dwc ----------------
// block = (b,h), 256 threads (4 waves). LDS union, 65440 B:
//  R1 @0     : Ks   [196][36] u16 (phase A->B; stray reads to row 207 stay in R1)
//              AVt  [32][68]  u16 @0     (C->E)
//              dwcs [196][32] u16 @4352  (C2->E)
//  R2 @16896 : P1s  [64][228] u16 (A(zero)/B->C)   |  P2s [208][68] u16 (D->E)
//  R3 @46080 : Vs   [196][36] u16 (A->C2)
//  R4 @60192 : ags  [64][36]  u16 (A->D)
//  R5 @64800 : dwcw [10][32]  u16 (A->C2)
#define OFF_KS   0
#define OFF_AVT  0
#define OFF_DWCS 4352
#define OFF_P1   16896
#define OFF_P2   16896
#define OFF_VS   46080
#define OFF_AGS  60192
#define OFF_DWCW 64800
#define SMEM_BYTES 65440

__global__ __launch_bounds__(256) void k_fused(const u16* __restrict__ qkv,
    const float* __restrict__ bias1, const float* __restrict__ bias2,
    const float* __restrict__ dwc_w, const float* __restrict__ dwc_b,
    u16* __restrict__ t) {
  __shared__ __align__(16) char smem[SMEM_BYTES];
  u16* Ks   = (u16*)(smem + OFF_KS);
  u16* AVt  = (u16*)(smem + OFF_AVT);
  u16* dwcs = (u16*)(smem + OFF_DWCS);
  u16* P1s  = (u16*)(smem + OFF_P1);
  u16* P2s  = (u16*)(smem + OFF_P2);
  u16* Vs   = (u16*)(smem + OFF_VS);
  u16* ags  = (u16*)(smem + OFF_AGS);
  u16* dwcw = (u16*)(smem + OFF_DWCW);

  const int bh = blockIdx.x, b = bh / 12, h = bh % 12;
  const int tid = threadIdx.x;
  const int lane = tid & 63, w = tid >> 6;
  const int quad = lane >> 4, m16 = lane & 15;
  const long qkvb = (long)b * 196 * 1152;
  const f32x4 zf = {0.f, 0.f, 0.f, 0.f};

  // ===== Phase A: stage K,V, dwc weights, pooled agents; zero P1s =====
  for (int i = tid; i < 7296; i += 256) ((u32*)P1s)[i] = 0;
  if (tid < 196) {
    const uint2* k2p = (const uint2*)(qkv + qkvb + (long)tid * 1152 + 384 + h * 32);
    const uint2* v2p = (const uint2*)(qkv + qkvb + (long)tid * 1152 + 768 + h * 32);
    uint2* kd = (uint2*)&Ks[tid * 36];
    uint2* vd = (uint2*)&Vs[tid * 36];
#pragma unroll
    for (int i = 0; i < 8; ++i) { kd[i] = k2p[i]; vd[i] = v2p[i]; }
  }
  for (int i = tid; i < 320; i += 256) {
    int tap = i >> 5, ch = i & 31;
    float v = (tap < 9) ? dwc_w[(h * 32 + ch) * 9 + tap] : dwc_b[h * 32 + ch];
    dwcw[tap * 32 + ch] = f2bf(v);
  }
  for (int i = tid; i < 784; i += 256) {  // 49 agents x 16 ch-pairs
    int a = i >> 4, cp = i & 15;
    int ay = a / 7, ax = a % 7;
    int y0 = ay * 2, x0 = ax * 2;
    const u16* q0 = qkv + qkvb + h * 32 + cp * 2;
    u32 v00 = *(const u32*)(q0 + (long)(y0 * 14 + x0) * 1152);
    u32 v01 = *(const u32*)(q0 + (long)(y0 * 14 + x0 + 1) * 1152);
    u32 v10 = *(const u32*)(q0 + (long)((y0 + 1) * 14 + x0) * 1152);
    u32 v11 = *(const u32*)(q0 + (long)((y0 + 1) * 14 + x0 + 1) * 1152);
    float lo = 0.25f * (bf2f((u16)(v00 & 0xffff)) + bf2f((u16)(v01 & 0xffff))
                      + bf2f((u16)(v10 & 0xffff)) + bf2f((u16)(v11 & 0xffff)));
    float hi = 0.25f * (bf2f((u16)(v00 >> 16)) + bf2f((u16)(v01 >> 16))
                      + bf2f((u16)(v10 >> 16)) + bf2f((u16)(v11 >> 16)));
    *(u32*)&ags[a * 36 + cp * 2] = (u32)f2bf(lo) | ((u32)f2bf(hi) << 16);
  }
  __syncthreads();

  // ===== Phase B: S1 = softmax_n(SCALE*ag.K^T + bias1); wave w owns agents 16w.. =====
  {
    bf16x8 av = lds8(&ags[(16 * w + m16) * 36 + quad * 8]);
    f32x4 acc[13];
#pragma unroll
    for (int nt = 0; nt < 13; ++nt) {
      bf16x8 bv = lds8(&Ks[(nt * 16 + m16) * 36 + quad * 8]);
      acc[nt] = __builtin_amdgcn_mfma_f32_16x16x32_bf16(av, bv, zf, 0, 0, 0);
    }
    const float* b1 = bias1 + (long)h * 49 * 196;
    float rs[4] = {0.f, 0.f, 0.f, 0.f};
#pragma unroll
    for (int nt = 0; nt < 13; ++nt) {
      int token = nt * 16 + m16;
#pragma unroll
      for (int r = 0; r < 4; ++r) {
        int agent = 16 * w + quad * 4 + r;
        float e = 0.f;
        if (agent < 49 && token < 196)
          e = __expf(acc[nt][r] * SCALE + b1[agent * 196 + token]);
        acc[nt][r] = e;
        rs[r] += e;
      }
    }
    float inv[4];
#pragma unroll
    for (int r = 0; r < 4; ++r) {
      rs[r] += __shfl_xor(rs[r], 1);
      rs[r] += __shfl_xor(rs[r], 2);
      rs[r] += __shfl_xor(rs[r], 4);
      rs[r] += __shfl_xor(rs[r], 8);
      inv[r] = 1.f / rs[r];
    }
#pragma unroll
    for (int nt = 0; nt < 13; ++nt) {
      int token = nt * 16 + m16;
#pragma unroll
      for (int r = 0; r < 4; ++r) {
        int agent = 16 * w + quad * 4 + r;
        if (agent < 49 && token < 196)
          P1s[agent * 228 + token] = f2bf(acc[nt][r] * inv[r]);
      }
    }
  }
  __syncthreads();  // Ks region about to be overwritten (AVt); P1s rows cross-checked

  // ===== Phase C: agent_v^T: AV = P1 @ V; write AVt[ch][agent] =====
  {
    f32x4 avacc[2] = {zf, zf};
    for (int k7 = 0; k7 < 7; ++k7) {
      bf16x8 ap = lds8(&P1s[(16 * w + m16) * 228 + k7 * 32 + quad * 8]);
#pragma unroll
      for (int nt = 0; nt < 2; ++nt) {
        union { u16 s[8]; bf16x8 v; } bp;
#pragma unroll
        for (int j = 0; j < 8; ++j) {
          int tok = k7 * 32 + quad * 8 + j;
          bp.s[j] = (tok < 196) ? Vs[tok * 36 + nt * 16 + m16] : (u16)0;
        }
        avacc[nt] = __builtin_amdgcn_mfma_f32_16x16x32_bf16(ap, bp.v, avacc[nt], 0, 0, 0);
      }
    }
#pragma unroll
    for (int nt = 0; nt < 2; ++nt)
#pragma unroll
      for (int r = 0; r < 4; ++r)
        AVt[(nt * 16 + m16) * 68 + 16 * w + quad * 4 + r] = f2bf(avacc[nt][r]);
  }

  // ===== Phase C2: depthwise 3x3 from Vs -> dwcs (thread = ch-pair x token-slot) =====
  {
    int cp = tid & 15, slot = tid >> 4;
    float wv[20];
#pragma unroll
    for (int tp = 0; tp < 10; ++tp) {
      u32 ww = *(const u32*)&dwcw[tp * 32 + cp * 2];
      wv[2 * tp] = bf2f((u16)(ww & 0xffff));
      wv[2 * tp + 1] = bf2f((u16)(ww >> 16));
    }
    for (int token = slot; token < 196; token += 16) {
      int y = token / 14, x = token % 14;
      float a0 = wv[18], a1 = wv[19];
      int tap = 0;
      for (int dy = -1; dy <= 1; ++dy) {
        int yy = y + dy;
        for (int dx = -1; dx <= 1; ++dx, ++tap) {
          int xx = x + dx;
          if (yy < 0 || yy > 13 || xx < 0 || xx > 13) continue;
          u32 vv = *(const u32*)&Vs[(yy * 14 + xx) * 36 + cp * 2];
          a0 += wv[2 * tap] * bf2f((u16)(vv & 0xffff));
          a1 += wv[2 * tap + 1] * bf2f((u16)(vv >> 16));
        }
      }
      *(u32*)&dwcs[token * 32 + cp * 2] = (u32)f2bf(a0) | ((u32)f2bf(a1) << 16);
    }
  }
  __syncthreads();  // AVt/dwcs ready for all waves; P1s free for P2s

  // ===== Phase D+E: per m-tile: S2 softmax -> P2s -> Out = P2 @ AV (+dwc) -> t =====
  const float* b2 = bias2 + (long)h * 196 * 49;
  for (int mt = w; mt < 13; mt += 4) {
    int tka = mt * 16 + m16; if (tka > 195) tka = 195;
    bf16x8 aq = *(const bf16x8*)(qkv + qkvb + (long)tka * 1152 + h * 32 + quad * 8);
    f32x4 sacc[4];
#pragma unroll
    for (int nt = 0; nt < 4; ++nt) {
      bf16x8 bv = lds8(&ags[(nt * 16 + m16) * 36 + quad * 8]);
      sacc[nt] = __builtin_amdgcn_mfma_f32_16x16x32_bf16(aq, bv, zf, 0, 0, 0);
    }
    float rs[4] = {0.f, 0.f, 0.f, 0.f};
#pragma unroll
    for (int nt = 0; nt < 4; ++nt) {
      int agent = nt * 16 + m16;
#pragma unroll
      for (int r = 0; r < 4; ++r) {
        int token = mt * 16 + quad * 4 + r; if (token > 195) token = 195;
        float e = 0.f;
        if (agent < 49)
          e = __expf(sacc[nt][r] * SCALE + b2[token * 49 + agent]);
        sacc[nt][r] = e;
        rs[r] += e;
      }
    }
    float inv[4];
#pragma unroll
    for (int r = 0; r < 4; ++r) {
      rs[r] += __shfl_xor(rs[r], 1);
      rs[r] += __shfl_xor(rs[r], 2);
      rs[r] += __shfl_xor(rs[r], 4);
      rs[r] += __shfl_xor(rs[r], 8);
      inv[r] = 1.f / rs[r];
    }
#pragma unroll
    for (int nt = 0; nt < 4; ++nt)
#pragma unroll
      for (int r = 0; r < 4; ++r)
        P2s[(mt * 16 + quad * 4 + r) * 68 + nt * 16 + m16] = f2bf(sacc[nt][r] * inv[r]);
    // Out = P2 @ AV  (same-wave LDS write->read: DS is in-order per wave)
    f32x4 oacc[2] = {zf, zf};
#pragma unroll
    for (int k2 = 0; k2 < 2; ++k2) {
      bf16x8 ap = lds8(&P2s[(mt * 16 + m16) * 68 + k2 * 32 + quad * 8]);
#pragma unroll
      for (int nt2 = 0; nt2 < 2; ++nt2) {
        bf16x8 bv = lds8(&AVt[(nt2 * 16 + m16) * 68 + k2 * 32 + quad * 8]);
        oacc[nt2] = __builtin_amdgcn_mfma_f32_16x16x32_bf16(ap, bv, oacc[nt2], 0, 0, 0);
      }
    }
#pragma unroll
    for (int nt2 = 0; nt2 < 2; ++nt2)
#pragma unroll
      for (int r = 0; r < 4; ++r) {
        int token = mt * 16 + quad * 4 + r;
        if (token < 196) {
          int ch = nt2 * 16 + m16;
          float val = oacc[nt2][r] + bf2f(dwcs[token * 32 + ch]);
          t[((long)(b * 196 + token)) * 384 + h * 32 + ch] = f2bf(val);
        }
      }
  }
}

extern "C" void kernel_launch(void* const* d_in, const int* in_sizes, int n_in,
                              void* d_out, int out_size, void* d_ws, size_t ws_size,
                              hipStream_t stream) {
  (void)in_sizes; (void)n_in; (void)out_size; (void)ws_size;
  const float* x      = (const float*)d_in[0];
  const float* qkv_w  = (const float*)d_in[1];
  const float* proj_w = (const float*)d_in[2];
  const float* proj_b = (const float*)d_in[3];
  const float* dwc_w  = (const float*)d_in[4];
  const float* dwc_b  = (const float*)d_in[5];
  const float* an_b   = (const float*)d_in[6];
  const float* ah_b   = (const float*)d_in[7];
  const float* aw_b   = (const float*)d_in[8];
  const float* na_b   = (const float*)d_in[9];
  const float* ha_b   = (const float*)d_in[10];
  const float* wa_b   = (const float*)d_in[11];
  float* out = (float*)d_out;

  // workspace layout (bytes), ~387.5 MB total:
  char* ws = (char*)d_ws;
  u16*   qkv     = (u16*)ws;                       // 231,211,008
  u16*   t       = (u16*)(ws + 231211008);         //  77,070,336
  u16*   xb      = (u16*)(ws + 308281344);         //  77,070,336
  u16*   wqkvb   = (u16*)(ws + 385351680);         //     884,736
  u16*   wprojb  = (u16*)(ws + 386236416);         //     294,912
  float* bias1   = (float*)(ws + 386531328);       //     460,992
  float* bias2   = (float*)(ws + 386992320);       //     460,992

  k_bias1<<<451, 256, 0, stream>>>(an_b, ah_b, aw_b, bias1);
  k_bias2<<<451, 256, 0, stream>>>(na_b, ha_b, wa_b, bias2);
  k_f2bf<<<18816, 256, 0, stream>>>(x, xb, (long)100352 * 384);
  k_f2bf<<<216, 256, 0, stream>>>(qkv_w, wqkvb, (long)1152 * 384);
  k_f2bf<<<72, 256, 0, stream>>>(proj_w, wprojb, (long)384 * 384);
  k_mfma_qkv<<<dim3(9, 784), 256, 0, stream>>>(xb, wqkvb, qkv);
  k_fused<<<6144, 256, 0, stream>>>(qkv, bias1, bias2, dwc_w, dwc_b, t);
  k_mfma_out<<<dim3(3, 784), 256, 0, stream>>>(t, wprojb, proj_b, out);
}